// Round 1
// baseline (627.011 us; speedup 1.0000x reference)
//
#include <hip/hip_runtime.h>
#include <stdint.h>
#include <stddef.h>

// Problem sizes (fixed by reference): B=8, T=48 -> BT=384, N=1024, D=64, G=256.
// All inputs fp32. Output fp32 [384][256][64].
//
// Pipeline:
//  K0: view -> view_hi/view_lo bf16 planes; vb[g][d] = sum_n view[g][n]*b[n][d]
//  K1: h[bt][n][d] = sum_i x[bt][n][i]*w[n][i][d]  (fp32 VALU, exact)
//      stored as bf16 hi/lo pair, n-fastest interleaved: h[bt][d][nc=n/8][pl][8n]
//  K2: out = LayerNorm( view @ h + vb )  via split-bf16 MFMA (3 terms)

#define LNEPS 1e-5f

typedef __attribute__((ext_vector_type(8))) short bf16x8;
typedef __attribute__((ext_vector_type(4))) float f32x4;

__device__ __forceinline__ unsigned short f32_bf16(float f) {
    unsigned u = __float_as_uint(f);
    u += 0x7FFFu + ((u >> 16) & 1u);
    return (unsigned short)(u >> 16);
}
__device__ __forceinline__ float bf16_f32(unsigned short h) {
    return __uint_as_float(((unsigned)h) << 16);
}

__device__ __forceinline__ void gll16(const void* g, void* l) {
    __builtin_amdgcn_global_load_lds(
        (const __attribute__((address_space(1))) void*)g,
        (__attribute__((address_space(3))) void*)l, 16, 0, 0);
}

// ws layout (bytes):
//  h      : 0          .. 100663296   (384*64*1024*2 bf16 * 2 planes interleaved)
//  view_hi: 100663296  .. +524288
//  view_lo: 101187584  .. +524288
//  vb     : 101711872  .. +65536
#define WS_H   0
#define WS_VH  100663296u
#define WS_VL  101187584u
#define WS_VB  101711872u

// ---------------------------------------------------------------- K0: prep
__global__ __launch_bounds__(64) void k0_prep(
        const float* __restrict__ view, const float* __restrict__ bias,
        unsigned short* __restrict__ vh, unsigned short* __restrict__ vl,
        float* __restrict__ vb) {
    const int g = blockIdx.x;   // 0..255
    const int d = threadIdx.x;  // 0..63
    // split view row g into bf16 hi/lo
    #pragma unroll
    for (int k = 0; k < 16; ++k) {
        int idx = g * 1024 + k * 64 + d;
        float v = view[idx];
        unsigned short hi = f32_bf16(v);
        unsigned short lo = f32_bf16(v - bf16_f32(hi));
        vh[idx] = hi; vl[idx] = lo;
    }
    // vb[g][d] = sum_n view[g][n] * b[n][d]   (fp32, exact bias fold)
    float a = 0.f;
    const float* vrow = view + g * 1024;
    #pragma unroll 4
    for (int n = 0; n < 1024; ++n)
        a = fmaf(vrow[n], bias[n * 64 + d], a);
    vb[g * 64 + d] = a;
}

// ---------------------------------------------------------------- K1: node linear
// grid 512 = 128 n-groups(8 n) x 4 bt-groups(96 bt); block 1024 = 8 nl x 64 d x 2 ih
// thread: caches w[n][ih*32..+31][d] in 32 VGPRs; loops bt; partial-sum pairs
// combined through LDS; hi/lo split; LDS micro-transpose -> coalesced 32B runs.
#define K1_PREF(BT_IDX, XR) do {                                             \
    const float4* xp_ = (const float4*)(xbase + (size_t)(BT_IDX) * 65536u);  \
    _Pragma("unroll")                                                        \
    for (int q_ = 0; q_ < 8; ++q_) XR[q_] = xp_[q_];                         \
} while (0)

#define K1_BODY(BT_IDX, XR, PARITY) do {                                     \
    float acc_ = 0.f;                                                        \
    _Pragma("unroll")                                                        \
    for (int q_ = 0; q_ < 8; ++q_) {                                         \
        acc_ = fmaf(XR[q_].x, wreg[4*q_+0], acc_);                           \
        acc_ = fmaf(XR[q_].y, wreg[4*q_+1], acc_);                           \
        acc_ = fmaf(XR[q_].z, wreg[4*q_+2], acc_);                           \
        acc_ = fmaf(XR[q_].w, wreg[4*q_+3], acc_);                           \
    }                                                                        \
    if (ih == 1) pbuf[nl][d] = acc_;                                         \
    __syncthreads();                                                         \
    if (ih == 0) {                                                           \
        float hv_ = acc_ + pbuf[nl][d];                                      \
        unsigned short hi_ = f32_bf16(hv_);                                  \
        unsigned short lo_ = f32_bf16(hv_ - bf16_f32(hi_));                  \
        tbuf[PARITY][d][nl] = ((unsigned)hi_ << 16) | (unsigned)lo_;         \
    }                                                                        \
    __syncthreads();                                                         \
    if (tid < 512) {                                                         \
        unsigned t0_ = tbuf[PARITY][wd][2*wq];                               \
        unsigned t1_ = tbuf[PARITY][wd][2*wq+1];                             \
        unsigned dw_ = (wpl == 0) ? ((t0_ >> 16) | (t1_ & 0xFFFF0000u))      \
                                  : ((t0_ & 0xFFFFu) | (t1_ << 16));         \
        hw[(size_t)(BT_IDX) * 65536u + (unsigned)wd * 1024u +                \
           (unsigned)ng * 8u + (unsigned)wpl * 4u + (unsigned)wq] = dw_;     \
    }                                                                        \
} while (0)

__global__ __launch_bounds__(1024, 4) void k1_node(
        const float* __restrict__ x, const float* __restrict__ w,
        unsigned* __restrict__ hw) {
    const int tid = threadIdx.x;
    const int d   = tid & 63;
    const int nl  = (tid >> 6) & 7;
    const int ih  = tid >> 9;            // 0/1: i-half
    const int ng  = blockIdx.x & 127;    // n-group of 8
    const int btg = blockIdx.x >> 7;     // 0..3
    const int n   = ng * 8 + nl;
    const int bt0 = btg * 96;
    // writer role decode (tid<512): 1 dword = 2 n of one plane
    const int wd  = tid >> 3;
    const int wpl = (tid >> 2) & 1;
    const int wq  = tid & 3;

    __shared__ float pbuf[8][64];
    __shared__ unsigned tbuf[2][64][9];  // [parity][d][nl(+pad)]

    // w register cache: w[n][ih*32 + i][d], i=0..31
    float wreg[32];
    const float* wp = w + (size_t)n * 4096 + (size_t)ih * 2048 + d;
    #pragma unroll
    for (int i = 0; i < 32; ++i) wreg[i] = wp[(size_t)i * 64];

    const float* xbase = x + (size_t)n * 64 + (size_t)ih * 32;
    float4 xa[8], xc[8];
    K1_PREF(bt0, xa);
    for (int it = 0; it < 96; it += 2) {
        K1_PREF(bt0 + it + 1, xc);
        K1_BODY(bt0 + it, xa, 0);
        if (it + 2 < 96) K1_PREF(bt0 + it + 2, xa);
        K1_BODY(bt0 + it + 1, xc, 1);
    }
}

// ---------------------------------------------------------------- K2: grid agg + LN
// grid 384 (one block per bt); block 512 (8 waves); BM=256(all G), BN=64(all D), BK=32.
// LDS per kbuf: A[256 rows][8 slots]*16B = 32768  +  B[64 d][8 slots]*16B = 8192.
// Slot content XOR-swizzled by (row&7)/(d&7) via pre-swizzled global gather.
#define KBUF 40960

__global__ __launch_bounds__(512, 4) void k2_grid(
        const unsigned short* __restrict__ vh, const unsigned short* __restrict__ vl,
        const unsigned char* __restrict__ hb, const float* __restrict__ vb,
        const float* __restrict__ gamma, const float* __restrict__ beta,
        float* __restrict__ out) {
    __shared__ __align__(16) unsigned char smem[2 * KBUF];
    const int tid = threadIdx.x;
    const int l   = tid & 63;
    const int wv  = tid >> 6;      // 0..7
    const int bt  = blockIdx.x;    // 0..383
    const int lc  = l & 15;
    const int lg  = l >> 4;

    // ---- staging descriptors (computed once) ----
    // A: 4 calls/wave: linear slot id = (wv*4+c)*64 + l ; row=id>>3, slot=id&7
    //    sg = slot ^ (row&7): pl_g = sg>>2, kc_g = sg&3
    const unsigned short* a_src[4];
    int a_dst[4];
    #pragma unroll
    for (int c = 0; c < 4; ++c) {
        int id   = (wv * 4 + c) * 64 + l;
        int row  = id >> 3;
        int slot = id & 7;
        int sg   = slot ^ (row & 7);
        int plg  = sg >> 2;
        int kcg  = sg & 3;
        const unsigned short* pl = plg ? vl : vh;
        a_src[c] = pl + (size_t)row * 1024 + kcg * 8;   // + s*32 per step
        a_dst[c] = (wv * 4 + c) * 1024;
    }
    // B: 1 call/wave: id = wv*64 + l ; d=id>>3, slot=id&7
    const unsigned char* b_src;
    int b_dst;
    {
        int id   = wv * 64 + l;
        int d_   = id >> 3;
        int slot = id & 7;
        int sg   = slot ^ (d_ & 7);
        int kcg  = sg >> 1;
        int plg  = sg & 1;
        b_src = hb + (size_t)bt * 262144u + (size_t)d_ * 4096u
                   + (size_t)kcg * 32u + (size_t)plg * 16u;  // + s*128 per step
        b_dst = 32768 + wv * 1024;
    }
    // ---- fragment read offsets (lane-constant) ----
    int aoff[2][2];
    #pragma unroll
    for (int st = 0; st < 2; ++st)
        #pragma unroll
        for (int pl = 0; pl < 2; ++pl) {
            int row = wv * 32 + st * 16 + lc;
            aoff[st][pl] = row * 128 + ((((pl << 2) | lg) ^ (row & 7)) * 16);
        }
    int boff[4][2];
    #pragma unroll
    for (int cs = 0; cs < 4; ++cs)
        #pragma unroll
        for (int pl = 0; pl < 2; ++pl) {
            int d_ = cs * 16 + lc;
            boff[cs][pl] = 32768 + d_ * 128 + ((((lg << 1) | pl) ^ (d_ & 7)) * 16);
        }

    f32x4 acc[2][4];
    #pragma unroll
    for (int st = 0; st < 2; ++st)
        #pragma unroll
        for (int cs = 0; cs < 4; ++cs)
            acc[st][cs] = (f32x4){0.f, 0.f, 0.f, 0.f};

#define K2_STAGE(KB, S) do {                                                  \
    _Pragma("unroll")                                                         \
    for (int c_ = 0; c_ < 4; ++c_)                                            \
        gll16(a_src[c_] + (size_t)(S) * 32, smem + (KB) + a_dst[c_]);         \
    gll16(b_src + (size_t)(S) * 128, smem + (KB) + b_dst);                    \
} while (0)

    K2_STAGE(0, 0);
    __syncthreads();
    int kb = 0;
    for (int s = 0; s < 32; ++s) {
        if (s + 1 < 32) K2_STAGE(kb ^ KBUF, s + 1);
        bf16x8 a0h = *(const bf16x8*)(smem + kb + aoff[0][0]);
        bf16x8 a0l = *(const bf16x8*)(smem + kb + aoff[0][1]);
        bf16x8 a1h = *(const bf16x8*)(smem + kb + aoff[1][0]);
        bf16x8 a1l = *(const bf16x8*)(smem + kb + aoff[1][1]);
        #pragma unroll
        for (int cs = 0; cs < 4; ++cs) {
            bf16x8 bh = *(const bf16x8*)(smem + kb + boff[cs][0]);
            bf16x8 bl = *(const bf16x8*)(smem + kb + boff[cs][1]);
            acc[0][cs] = __builtin_amdgcn_mfma_f32_16x16x32_bf16(a0h, bh, acc[0][cs], 0, 0, 0);
            acc[0][cs] = __builtin_amdgcn_mfma_f32_16x16x32_bf16(a0h, bl, acc[0][cs], 0, 0, 0);
            acc[0][cs] = __builtin_amdgcn_mfma_f32_16x16x32_bf16(a0l, bh, acc[0][cs], 0, 0, 0);
            acc[1][cs] = __builtin_amdgcn_mfma_f32_16x16x32_bf16(a1h, bh, acc[1][cs], 0, 0, 0);
            acc[1][cs] = __builtin_amdgcn_mfma_f32_16x16x32_bf16(a1h, bl, acc[1][cs], 0, 0, 0);
            acc[1][cs] = __builtin_amdgcn_mfma_f32_16x16x32_bf16(a1l, bh, acc[1][cs], 0, 0, 0);
        }
        __syncthreads();
        kb ^= KBUF;
    }

    // ---- epilogue: + vb, LayerNorm over D=64, store fp32 ----
    float gam[4], bet[4];
    #pragma unroll
    for (int cs = 0; cs < 4; ++cs) {
        gam[cs] = gamma[cs * 16 + lc];
        bet[cs] = beta[cs * 16 + lc];
    }
    #pragma unroll
    for (int st = 0; st < 2; ++st) {
        #pragma unroll
        for (int j = 0; j < 4; ++j) {
            int g = wv * 32 + st * 16 + lg * 4 + j;  // D/C: col=lane&15, row=(lane>>4)*4+reg
            float v[4];
            float s1 = 0.f, s2 = 0.f;
            #pragma unroll
            for (int cs = 0; cs < 4; ++cs) {
                v[cs] = acc[st][cs][j] + vb[g * 64 + cs * 16 + lc];
                s1 += v[cs];
                s2 += v[cs] * v[cs];
            }
            s1 += __shfl_xor(s1, 1);  s2 += __shfl_xor(s2, 1);
            s1 += __shfl_xor(s1, 2);  s2 += __shfl_xor(s2, 2);
            s1 += __shfl_xor(s1, 4);  s2 += __shfl_xor(s2, 4);
            s1 += __shfl_xor(s1, 8);  s2 += __shfl_xor(s2, 8);
            float mu  = s1 * 0.015625f;
            float var = s2 * 0.015625f - mu * mu;
            float inv = rsqrtf(var + LNEPS);
            size_t ob = (size_t)bt * 16384u + (size_t)g * 64u;
            #pragma unroll
            for (int cs = 0; cs < 4; ++cs)
                out[ob + cs * 16 + lc] = (v[cs] - mu) * inv * gam[cs] + bet[cs];
        }
    }
}

// ---------------------------------------------------------------- launch
extern "C" void kernel_launch(void* const* d_in, const int* in_sizes, int n_in,
                              void* d_out, int out_size, void* d_ws, size_t ws_size,
                              hipStream_t stream) {
    (void)in_sizes; (void)n_in; (void)out_size; (void)ws_size;
    const float* x     = (const float*)d_in[0];
    const float* view  = (const float*)d_in[1];
    const float* w     = (const float*)d_in[2];
    const float* bias  = (const float*)d_in[3];
    const float* gamma = (const float*)d_in[4];
    const float* beta  = (const float*)d_in[5];
    float* out = (float*)d_out;

    char* ws = (char*)d_ws;
    unsigned* hw        = (unsigned*)(ws + WS_H);
    unsigned short* vh  = (unsigned short*)(ws + WS_VH);
    unsigned short* vl  = (unsigned short*)(ws + WS_VL);
    float* vb           = (float*)(ws + WS_VB);

    hipLaunchKernelGGL(k0_prep, dim3(256), dim3(64), 0, stream,
                       view, bias, vh, vl, vb);
    hipLaunchKernelGGL(k1_node, dim3(512), dim3(1024), 0, stream, x, w, hw);
    hipLaunchKernelGGL(k2_grid, dim3(384), dim3(512), 0, stream,
                       vh, vl, (const unsigned char*)(ws + WS_H), vb, gamma, beta, out);
}

// Round 3
// 270.055 us; speedup vs baseline: 2.3218x; 2.3218x over previous
//
#include <hip/hip_runtime.h>
#include <stdint.h>
#include <stddef.h>

// Sizes fixed by reference: B*T=384, N=1024, D=64, G=256. All fp32.
// K0: view -> bf16 hi/lo planes; vb[g][d] = sum_n view[g][n]*b[n][d] (exact fold)
// K1: h[bt][n][d] = sum_i x[bt][n][i]*w[n][i][d] via split-bf16 MFMA (4 terms ~ exact)
//     h stored split-bf16, layout hb[bt][d][n/16][pl][n%16] (64-B runs per (bt,d))
// K2: out = LayerNorm(view @ h + vb) via split-bf16 MFMA (3 terms), BM=128,
//     grid 768 with XCD-paired remap so the two bm-halves of one bt share L2.

#define LNEPS 1e-5f

typedef __attribute__((ext_vector_type(8))) short bf16x8;
typedef __attribute__((ext_vector_type(4))) float f32x4;
typedef union { unsigned u[4]; bf16x8 v; } fragu;

static __device__ __forceinline__ unsigned rne(unsigned u) {
    return u + 0x7FFFu + ((u >> 16) & 1u);
}
// split (a,b) into packed bf16-hi dword and bf16-lo dword (lo = rounded residual)
static __device__ __forceinline__ void split_pair(float a, float b,
                                                  unsigned& hw_, unsigned& lw_) {
    unsigned ra = rne(__float_as_uint(a));
    unsigned rb = rne(__float_as_uint(b));
    hw_ = (ra >> 16) | (rb & 0xFFFF0000u);
    float fa = a - __uint_as_float(ra & 0xFFFF0000u);
    float fb = b - __uint_as_float(rb & 0xFFFF0000u);
    unsigned sa = rne(__float_as_uint(fa));
    unsigned sb = rne(__float_as_uint(fb));
    lw_ = (sa >> 16) | (sb & 0xFFFF0000u);
}
// single float -> (hi16<<16)|lo16
static __device__ __forceinline__ unsigned packhl(float vv) {
    unsigned r = rne(__float_as_uint(vv));
    unsigned hif = r & 0xFFFF0000u;
    float res = vv - __uint_as_float(hif);
    unsigned s = rne(__float_as_uint(res));
    return hif | (s >> 16);
}

static __device__ __forceinline__ void gll16(const void* g, void* l) {
    __builtin_amdgcn_global_load_lds(
        (const __attribute__((address_space(1))) void*)g,
        (__attribute__((address_space(3))) void*)l, 16, 0, 0);
}

// ws layout (bytes)
#define WS_H   0u           // 384*64*1024*2*2 = 100663296
#define WS_VH  100663296u   // +524288
#define WS_VL  101187584u   // +524288
#define WS_VB  101711872u   // +65536

// ---------------------------------------------------------------- K0
__global__ __launch_bounds__(256) void k0_prep(
        const float* __restrict__ view, const float* __restrict__ bias,
        unsigned short* __restrict__ vh, unsigned short* __restrict__ vl,
        float* __restrict__ vb) {
    const int g = blockIdx.x;    // 0..255
    const int tid = threadIdx.x; // 0..255
    float4 vv = *(const float4*)(view + g * 1024 + tid * 4);
    unsigned h01, l01, h23, l23;
    split_pair(vv.x, vv.y, h01, l01);
    split_pair(vv.z, vv.w, h23, l23);
    *(uint2*)(vh + g * 1024 + tid * 4) = make_uint2(h01, h23);
    *(uint2*)(vl + g * 1024 + tid * 4) = make_uint2(l01, l23);
    const int q = tid >> 6, d = tid & 63;
    const float* vrow = view + g * 1024;
    float a = 0.f;
    #pragma unroll 8
    for (int nn = q * 256; nn < q * 256 + 256; ++nn)
        a = fmaf(vrow[nn], bias[nn * 64 + d], a);
    __shared__ float red[4][64];
    red[q][d] = a;
    __syncthreads();
    if (tid < 64)
        vb[g * 64 + tid] = red[0][tid] + red[1][tid] + red[2][tid] + red[3][tid];
}

// ---------------------------------------------------------------- K1
// grid 256 = 64 ng(16 n) x 4 btg(96 bt); block 1024 = 16 waves, wave wv owns n=ng*16+wv.
// LDS: xs = x tile [16 bt][16 n][64 i] fp32 (ib-swizzled, 64KB) via global_load_lds;
//      T  = transpose tile [16 n][16 bt][68 pad] u32 (69.6KB).
// Per tile: frag-read x -> barrier -> stage next + 32 MFMA + pack->T -> barrier
//           -> transposed 64-B global stores -> (loop barrier).
__global__ __launch_bounds__(1024, 4) void k1_node(
        const float* __restrict__ x, const float* __restrict__ w,
        unsigned char* __restrict__ hb) {
    __shared__ float xs[16 * 16 * 64];
    __shared__ unsigned T[16 * 16 * 68];
    const int tid = threadIdx.x;
    const int l  = tid & 63, wv = tid >> 6;
    const int lc = l & 15,  lg = l >> 4;
    const int ng = blockIdx.x & 63, btg = blockIdx.x >> 6;
    const int n0 = ng * 16;
    const int bt_base = btg * 96;
    const int n = n0 + wv;

    // ---- w fragments for this wave's n (B operand: k=i, col=d) ----
    bf16x8 bh[4][2], bl[4][2];
    #pragma unroll
    for (int cs = 0; cs < 4; ++cs) {
        #pragma unroll
        for (int kc = 0; kc < 2; ++kc) {
            const float* wp = w + (size_t)n * 4096 + (size_t)(kc * 32 + lg * 8) * 64
                                + cs * 16 + lc;
            float e[8];
            #pragma unroll
            for (int j = 0; j < 8; ++j) e[j] = wp[(size_t)j * 64];
            fragu H, L;
            #pragma unroll
            for (int k2 = 0; k2 < 4; ++k2)
                split_pair(e[2 * k2], e[2 * k2 + 1], H.u[k2], L.u[k2]);
            bh[cs][kc] = H.v;
            bl[cs][kc] = L.v;
        }
    }

    // stage x tile T_ : 4096 units of 16 B, unit u = c*1024+tid
    // phys [btl][nn][ibp][half], ibg = ibp ^ (btl&7)
#define K1_STAGE(T_) do {                                                     \
    _Pragma("unroll")                                                         \
    for (int c_ = 0; c_ < 4; ++c_) {                                          \
        int u_ = c_ * 1024 + tid;                                             \
        int btl_ = u_ >> 8, r_ = u_ & 255;                                    \
        int nn_ = r_ >> 4, q_ = r_ & 15;                                      \
        int ibp_ = q_ >> 1, hf_ = q_ & 1;                                     \
        int ibg_ = ibp_ ^ (btl_ & 7);                                         \
        const unsigned char* src_ = (const unsigned char*)x                   \
            + (size_t)(bt_base + (T_) * 16 + btl_) * 262144u                  \
            + (size_t)(n0 + nn_) * 256u + ibg_ * 32 + hf_ * 16;               \
        gll16(src_, (unsigned char*)xs + c_ * 16384 + wv * 1024);             \
    }                                                                         \
} while (0)

    K1_STAGE(0);
    for (int t = 0; t < 6; ++t) {
        __syncthreads();  // x(t) ready; T free
        // A-frag reads: logical [bt=lc][n=wv][i=kc*32+lg*8 ..+7], ib-swizzled
        float4 xq[4];
        #pragma unroll
        for (int kc = 0; kc < 2; ++kc) {
            int ibp = (kc * 4 + lg) ^ (lc & 7);
            const float* rp = xs + lc * 1024 + wv * 64 + ibp * 8;
            xq[kc * 2]     = *(const float4*)(rp);
            xq[kc * 2 + 1] = *(const float4*)(rp + 4);
        }
        __syncthreads();  // x(t) consumed
        if (t < 5) K1_STAGE(t + 1);

        bf16x8 ah[2], al[2];
        #pragma unroll
        for (int kc = 0; kc < 2; ++kc) {
            fragu H, L;
            split_pair(xq[kc * 2].x,     xq[kc * 2].y,     H.u[0], L.u[0]);
            split_pair(xq[kc * 2].z,     xq[kc * 2].w,     H.u[1], L.u[1]);
            split_pair(xq[kc * 2 + 1].x, xq[kc * 2 + 1].y, H.u[2], L.u[2]);
            split_pair(xq[kc * 2 + 1].z, xq[kc * 2 + 1].w, H.u[3], L.u[3]);
            ah[kc] = H.v;
            al[kc] = L.v;
        }
        f32x4 acc[4];
        #pragma unroll
        for (int cs = 0; cs < 4; ++cs) acc[cs] = (f32x4){0.f, 0.f, 0.f, 0.f};
        #pragma unroll
        for (int cs = 0; cs < 4; ++cs) {
            #pragma unroll
            for (int kc = 0; kc < 2; ++kc) {
                acc[cs] = __builtin_amdgcn_mfma_f32_16x16x32_bf16(ah[kc], bh[cs][kc], acc[cs], 0, 0, 0);
                acc[cs] = __builtin_amdgcn_mfma_f32_16x16x32_bf16(ah[kc], bl[cs][kc], acc[cs], 0, 0, 0);
                acc[cs] = __builtin_amdgcn_mfma_f32_16x16x32_bf16(al[kc], bh[cs][kc], acc[cs], 0, 0, 0);
                acc[cs] = __builtin_amdgcn_mfma_f32_16x16x32_bf16(al[kc], bl[cs][kc], acc[cs], 0, 0, 0);
            }
        }
        // pack -> T[nn=wv][bt=lg*4+j][d=cs*16+lc]
        #pragma unroll
        for (int cs = 0; cs < 4; ++cs) {
            #pragma unroll
            for (int j = 0; j < 4; ++j)
                T[wv * 1088 + (lg * 4 + j) * 68 + cs * 16 + lc] = packhl(acc[cs][j]);
        }
        __syncthreads();  // T ready
        // transpose out: unit tid -> (btl, d); 64-B run = [pl hi 16n][pl lo 16n]
        {
            int btl = tid >> 6, d = tid & 63;
            unsigned vv[16];
            #pragma unroll
            for (int nn = 0; nn < 16; ++nn) vv[nn] = T[nn * 1088 + btl * 68 + d];
            unsigned hd[8], ld[8];
            #pragma unroll
            for (int k = 0; k < 8; ++k) {
                hd[k] = (vv[2 * k] >> 16) | (vv[2 * k + 1] & 0xFFFF0000u);
                ld[k] = (vv[2 * k] & 0xFFFFu) | (vv[2 * k + 1] << 16);
            }
            unsigned char* dst = hb + (size_t)(bt_base + t * 16 + btl) * 262144u
                                    + (size_t)d * 4096u + ng * 64;
            ((uint4*)dst)[0] = make_uint4(hd[0], hd[1], hd[2], hd[3]);
            ((uint4*)dst)[1] = make_uint4(hd[4], hd[5], hd[6], hd[7]);
            ((uint4*)dst)[2] = make_uint4(ld[0], ld[1], ld[2], ld[3]);
            ((uint4*)dst)[3] = make_uint4(ld[4], ld[5], ld[6], ld[7]);
        }
    }
#undef K1_STAGE
}

// ---------------------------------------------------------------- K2
// grid 768; remap so (bt,bm=0) and (bt,bm=1) land on the SAME XCD 8 dispatch
// slots apart: bm=(b>>3)&1, bt=(b&7)+(b>>4)*8  (XCD = b%8 round-robin).
// block 256 (4 waves); BM=128, BN=64, BK=32; LDS 2*(16K A + 8K B) = 48KB -> 3 blk/CU.
#define KB2 24576

__global__ __launch_bounds__(256, 3) void k2_grid(
        const unsigned short* __restrict__ vh, const unsigned short* __restrict__ vl,
        const unsigned char* __restrict__ hb, const float* __restrict__ vb,
        const float* __restrict__ gamma, const float* __restrict__ beta,
        float* __restrict__ out) {
    __shared__ __align__(16) unsigned char smem[2 * KB2];
    const int tid = threadIdx.x;
    const int l  = tid & 63;
    const int wv = tid >> 6;          // 0..3
    const int b  = blockIdx.x;
    const int bm = (b >> 3) & 1;
    const int bt = (b & 7) + (b >> 4) * 8;
    const int lc = l & 15, lg = l >> 4;

    // ---- A staging (view planes): 4 calls; id=(wv*4+c)*64+l; row=id>>3 (0..127) ----
    const unsigned short* a_src[4];
    int a_dst[4];
    #pragma unroll
    for (int c = 0; c < 4; ++c) {
        int id = (wv * 4 + c) * 64 + l;
        int row = id >> 3;
        int slot = id & 7;
        int sg = slot ^ (row & 7);
        int plg = sg >> 2, kcg = sg & 3;
        const unsigned short* pl = plg ? vl : vh;
        a_src[c] = pl + (size_t)(bm * 128 + row) * 1024 + kcg * 8;  // +s*32/step
        a_dst[c] = (wv * 4 + c) * 1024;
    }
    // ---- B staging (h): 2 calls; id=(wv*2+c)*64+l; d=id>>3 ----
    const unsigned char* b_src[2];
    int b_dst[2];
    #pragma unroll
    for (int c = 0; c < 2; ++c) {
        int id = (wv * 2 + c) * 64 + l;
        int d_ = id >> 3;
        int slot = id & 7;
        int sg = slot ^ (d_ & 7);
        b_src[c] = hb + (size_t)bt * 262144u + (size_t)d_ * 4096u
                      + (sg >> 2) * 64 + ((sg >> 1) & 1) * 32 + (sg & 1) * 16; // +s*128
        b_dst[c] = 16384 + (wv * 2 + c) * 1024;
    }
    // ---- fragment read offsets ----
    int aoff[2][2];
    #pragma unroll
    for (int st = 0; st < 2; ++st)
        #pragma unroll
        for (int pl = 0; pl < 2; ++pl) {
            int row = wv * 32 + st * 16 + lc;
            aoff[st][pl] = row * 128 + ((((pl << 2) | lg) ^ (row & 7)) * 16);
        }
    int boff[4][2];
    #pragma unroll
    for (int cs = 0; cs < 4; ++cs)
        #pragma unroll
        for (int pl = 0; pl < 2; ++pl) {
            int d_ = cs * 16 + lc;
            int sg = ((lg >> 1) << 2) | (pl << 1) | (lg & 1);
            boff[cs][pl] = 16384 + d_ * 128 + ((sg ^ (d_ & 7)) * 16);
        }

    f32x4 acc[2][4];
    #pragma unroll
    for (int st = 0; st < 2; ++st)
        #pragma unroll
        for (int cs = 0; cs < 4; ++cs)
            acc[st][cs] = (f32x4){0.f, 0.f, 0.f, 0.f};

#define K2_STAGE(KB, S) do {                                                  \
    _Pragma("unroll")                                                         \
    for (int c_ = 0; c_ < 4; ++c_)                                            \
        gll16(a_src[c_] + (size_t)(S) * 32, smem + (KB) + a_dst[c_]);         \
    _Pragma("unroll")                                                         \
    for (int c_ = 0; c_ < 2; ++c_)                                            \
        gll16(b_src[c_] + (size_t)(S) * 128, smem + (KB) + b_dst[c_]);        \
} while (0)

    K2_STAGE(0, 0);
    __syncthreads();
    int kb = 0;
    for (int s = 0; s < 32; ++s) {
        if (s + 1 < 32) K2_STAGE(kb ^ KB2, s + 1);
        bf16x8 a0h = *(const bf16x8*)(smem + kb + aoff[0][0]);
        bf16x8 a0l = *(const bf16x8*)(smem + kb + aoff[0][1]);
        bf16x8 a1h = *(const bf16x8*)(smem + kb + aoff[1][0]);
        bf16x8 a1l = *(const bf16x8*)(smem + kb + aoff[1][1]);
        #pragma unroll
        for (int cs = 0; cs < 4; ++cs) {
            bf16x8 bhf = *(const bf16x8*)(smem + kb + boff[cs][0]);
            bf16x8 blf = *(const bf16x8*)(smem + kb + boff[cs][1]);
            acc[0][cs] = __builtin_amdgcn_mfma_f32_16x16x32_bf16(a0h, bhf, acc[0][cs], 0, 0, 0);
            acc[0][cs] = __builtin_amdgcn_mfma_f32_16x16x32_bf16(a0h, blf, acc[0][cs], 0, 0, 0);
            acc[0][cs] = __builtin_amdgcn_mfma_f32_16x16x32_bf16(a0l, bhf, acc[0][cs], 0, 0, 0);
            acc[1][cs] = __builtin_amdgcn_mfma_f32_16x16x32_bf16(a1h, bhf, acc[1][cs], 0, 0, 0);
            acc[1][cs] = __builtin_amdgcn_mfma_f32_16x16x32_bf16(a1h, blf, acc[1][cs], 0, 0, 0);
            acc[1][cs] = __builtin_amdgcn_mfma_f32_16x16x32_bf16(a1l, bhf, acc[1][cs], 0, 0, 0);
        }
        __syncthreads();
        kb ^= KB2;
    }

    // ---- epilogue: +vb, LayerNorm over D=64, store ----
    float gam[4], bet[4];
    #pragma unroll
    for (int cs = 0; cs < 4; ++cs) {
        gam[cs] = gamma[cs * 16 + lc];
        bet[cs] = beta[cs * 16 + lc];
    }
    #pragma unroll
    for (int st = 0; st < 2; ++st) {
        #pragma unroll
        for (int j = 0; j < 4; ++j) {
            int g = bm * 128 + wv * 32 + st * 16 + lg * 4 + j;
            float v[4];
            float s1 = 0.f, s2 = 0.f;
            #pragma unroll
            for (int cs = 0; cs < 4; ++cs) {
                v[cs] = acc[st][cs][j] + vb[g * 64 + cs * 16 + lc];
                s1 += v[cs];
                s2 += v[cs] * v[cs];
            }
            s1 += __shfl_xor(s1, 1);  s2 += __shfl_xor(s2, 1);
            s1 += __shfl_xor(s1, 2);  s2 += __shfl_xor(s2, 2);
            s1 += __shfl_xor(s1, 4);  s2 += __shfl_xor(s2, 4);
            s1 += __shfl_xor(s1, 8);  s2 += __shfl_xor(s2, 8);
            float mu  = s1 * 0.015625f;
            float var = s2 * 0.015625f - mu * mu;
            float inv = rsqrtf(var + LNEPS);
            size_t ob = (size_t)bt * 16384u + (size_t)g * 64u;
            #pragma unroll
            for (int cs = 0; cs < 4; ++cs)
                out[ob + cs * 16 + lc] = (v[cs] - mu) * inv * gam[cs] + bet[cs];
        }
    }
#undef K2_STAGE
}

// ---------------------------------------------------------------- launch
extern "C" void kernel_launch(void* const* d_in, const int* in_sizes, int n_in,
                              void* d_out, int out_size, void* d_ws, size_t ws_size,
                              hipStream_t stream) {
    (void)in_sizes; (void)n_in; (void)out_size; (void)ws_size;
    const float* x     = (const float*)d_in[0];
    const float* view  = (const float*)d_in[1];
    const float* w     = (const float*)d_in[2];
    const float* bias  = (const float*)d_in[3];
    const float* gamma = (const float*)d_in[4];
    const float* beta  = (const float*)d_in[5];
    float* out = (float*)d_out;

    char* ws = (char*)d_ws;
    unsigned char* hb  = (unsigned char*)(ws + WS_H);
    unsigned short* vh = (unsigned short*)(ws + WS_VH);
    unsigned short* vl = (unsigned short*)(ws + WS_VL);
    float* vb          = (float*)(ws + WS_VB);

    hipLaunchKernelGGL(k0_prep, dim3(256), dim3(256), 0, stream,
                       view, bias, vh, vl, vb);
    hipLaunchKernelGGL(k1_node, dim3(256), dim3(1024), 0, stream, x, w, hb);
    hipLaunchKernelGGL(k2_grid, dim3(768), dim3(256), 0, stream,
                       vh, vl, hb, vb, gamma, beta, out);
}